// Round 4
// baseline (1340.535 us; speedup 1.0000x reference)
//
#include <hip/hip_runtime.h>
#include <hip/hip_bf16.h>

// QwenMoe: T=1024 H=2048 I=1408 E=60 SI=5632 topk=4, fp32 in/out.
// R4: LDS-free register-streaming GEMMs (flatmm-style): A bf16 direct to
// frags, B fp32 -> reg -> cvt_pk -> MFMA, 2-deep reg double-buffer, no
// barriers. Shared-down OVERWRITES out (no 8MB memset - fill node was 420us).

typedef float  f32x4  __attribute__((ext_vector_type(4)));
typedef short  bf16x8 __attribute__((ext_vector_type(8)));
typedef unsigned short u16;
typedef unsigned int   u32;

constexpr int TT = 1024, HD = 2048, ID = 1408, NE = 60, SID = 5632, KTOP = 4;

__device__ __forceinline__ u16 f2bf(float f) {
    union { float f; u32 u; } v; v.f = f;
    u32 r = v.u + 0x7FFFu + ((v.u >> 16) & 1u);   // RNE
    return (u16)(r >> 16);
}
__device__ __forceinline__ u32 cvtpk(float a, float b) {
    u32 r; asm("v_cvt_pk_bf16_f32 %0, %1, %2" : "=v"(r) : "v"(a), "v"(b));
    return r;
}
__device__ __forceinline__ bf16x8 cvt8(float4 a, float4 b) {
    union { u32 u[4]; bf16x8 v; } rr;
    rr.u[0] = cvtpk(a.x, a.y); rr.u[1] = cvtpk(a.z, a.w);
    rr.u[2] = cvtpk(b.x, b.y); rr.u[3] = cvtpk(b.z, b.w);
    return rr.v;
}
__device__ __forceinline__ bf16x8 asbf(uint4 v) {
    union { uint4 u; bf16x8 b; } c; c.u = v; return c.b;
}

// ---------------- tiny utility kernels ----------------
__global__ void zero_k(int* __restrict__ p) { p[threadIdx.x] = 0; }

__global__ __launch_bounds__(256) void xcvt_k(const float* __restrict__ x, u16* __restrict__ xb)
{
    // 1024*2048 elems; 512 blocks * 256 thr * 16 elems
    size_t i = ((size_t)blockIdx.x * 256 + threadIdx.x) * 16;
    const float4* p = (const float4*)(x + i);
    float4 f0 = p[0], f1 = p[1], f2 = p[2], f3 = p[3];
    uint4 o0, o1;
    o0.x = cvtpk(f0.x, f0.y); o0.y = cvtpk(f0.z, f0.w);
    o0.z = cvtpk(f1.x, f1.y); o0.w = cvtpk(f1.z, f1.w);
    o1.x = cvtpk(f2.x, f2.y); o1.y = cvtpk(f2.z, f2.w);
    o1.z = cvtpk(f3.x, f3.y); o1.w = cvtpk(f3.z, f3.w);
    ((uint4*)(xb + i))[0] = o0;
    ((uint4*)(xb + i))[1] = o1;
}

// ---------------- router ----------------
__global__ __launch_bounds__(64) void router_k(
    const float* __restrict__ x, const float* __restrict__ rw,
    const float* __restrict__ sgw,
    float* __restrict__ topk_p, int* __restrict__ topk_i,
    int* __restrict__ cnt, float* __restrict__ sgate)
{
    const int t = blockIdx.x, l = threadIdx.x;
    const float4* xr = ((const float4*)(x + (size_t)t * HD)) + l * 8;
    float4 xa[8];
    #pragma unroll
    for (int i = 0; i < 8; i++) xa[i] = xr[i];

    float le = 0.f;
    for (int e = 0; e < NE; e++) {
        const float4* wr = ((const float4*)(rw + (size_t)e * HD)) + l * 8;
        float a = 0.f;
        #pragma unroll
        for (int i = 0; i < 8; i++) {
            float4 wv = wr[i];
            a += xa[i].x * wv.x + xa[i].y * wv.y + xa[i].z * wv.z + xa[i].w * wv.w;
        }
        #pragma unroll
        for (int s = 32; s; s >>= 1) a += __shfl_xor(a, s);
        if (l == e) le = a;
    }
    {
        const float4* wr = ((const float4*)sgw) + l * 8;
        float a = 0.f;
        #pragma unroll
        for (int i = 0; i < 8; i++) {
            float4 wv = wr[i];
            a += xa[i].x * wv.x + xa[i].y * wv.y + xa[i].z * wv.z + xa[i].w * wv.w;
        }
        #pragma unroll
        for (int s = 32; s; s >>= 1) a += __shfl_xor(a, s);
        if (l == 0) sgate[t] = 1.f / (1.f + __expf(-a));
    }
    float mv = (l < NE) ? le : -3.4e38f;
    #pragma unroll
    for (int s = 32; s; s >>= 1) mv = fmaxf(mv, __shfl_xor(mv, s));
    float p = (l < NE) ? __expf(le - mv) : 0.f;
    float ss = p;
    #pragma unroll
    for (int s = 32; s; s >>= 1) ss += __shfl_xor(ss, s);
    p /= ss;
    float pv = (l < NE) ? p : -1.f;
    int   pi = l;
    float kp = 0.f; int ki = 0;
    for (int k = 0; k < KTOP; k++) {
        float bv = pv; int bi = pi;
        #pragma unroll
        for (int s = 32; s; s >>= 1) {
            float ov = __shfl_xor(bv, s); int oi = __shfl_xor(bi, s);
            if (ov > bv || (ov == bv && oi < bi)) { bv = ov; bi = oi; }
        }
        if (l == k) { kp = bv; ki = bi; }
        if (pi == bi) pv = -1.f;
    }
    if (l < KTOP) {
        topk_p[t * KTOP + l] = kp;
        topk_i[t * KTOP + l] = ki;
        atomicAdd(&cnt[ki], 1);
    }
}

__global__ __launch_bounds__(64) void prefix_k(const int* __restrict__ cnt, int* __restrict__ base)
{
    int l = threadIdx.x;
    if (l < NE) {
        int s = 0;
        for (int j = 0; j < l; j++) s += cnt[j];
        base[l] = s;
    }
}

__global__ __launch_bounds__(256) void scatter_k(
    const float* __restrict__ topk_p, const int* __restrict__ topk_i,
    const int* __restrict__ base, int* __restrict__ fill,
    int* __restrict__ slot_tok, float* __restrict__ slot_wt)
{
    int t = blockIdx.x * blockDim.x + threadIdx.x;
    if (t >= TT) return;
    for (int k = 0; k < KTOP; k++) {
        int e = topk_i[t * KTOP + k];
        int pos = atomicAdd(&fill[e], 1);
        int s = base[e] + pos;
        slot_tok[s] = t;
        slot_wt[s]  = topk_p[t * KTOP + k];
    }
}

// ------- fused gate+up, reg-streaming: H = silu(Xb@Wg^T)*(Xb@Wu^T)*wt -------
// Block: 256 thr = 4 waves (2M x 2N). Block tile M128 x N64. Wave M64 x N32.
// No LDS, no barriers. A bf16 direct frags; B fp32 -> cvt_pk.
template<bool GROUPED>
__global__ __launch_bounds__(256, 2) void gu_k(
    const u16* __restrict__ Xb,
    const float* __restrict__ Wg, const float* __restrict__ Wu, size_t bStride,
    u16* __restrict__ H,
    const int* __restrict__ slot_tok, const float* __restrict__ slot_wt,
    const int* __restrict__ cnt, const int* __restrict__ basearr,
    int K, int N)
{
    const int tid = threadIdx.x, w = tid >> 6, lane = tid & 63;
    const int lm = lane & 15, lk = lane >> 4;
    const int wm0 = (w >> 1) * 64, wn0 = (w & 1) * 32;
    const int e = GROUPED ? blockIdx.z : 0;
    const int mcnt = GROUPED ? cnt[e] : 128;
    const int mbase = GROUPED ? basearr[e] : 0;

    const float* gP[2]; const float* uP[2];
    #pragma unroll
    for (int nf = 0; nf < 2; nf++) {
        size_t row = (size_t)(blockIdx.x * 64 + wn0 + nf * 16 + lm);
        gP[nf] = Wg + (size_t)e * bStride + row * K + lk * 8;
        uP[nf] = Wu + (size_t)e * bStride + row * K + lk * 8;
    }

    for (int mt = 0; GROUPED ? (mt * 128 < mcnt) : (mt == 0); ++mt) {
        const u16* aP[4];
        #pragma unroll
        for (int mf = 0; mf < 4; mf++) {
            int mrow = wm0 + mf * 16 + lm;
            int row;
            if constexpr (GROUPED) {
                int sl = mbase + mt * 128 + mrow;
                row = (mt * 128 + mrow < mcnt) ? slot_tok[sl] : slot_tok[mbase];
            } else row = blockIdx.y * 128 + mrow;
            aP[mf] = Xb + (size_t)row * K + lk * 8;
        }

        f32x4 acc[2][4][2];
        #pragma unroll
        for (int m = 0; m < 2; m++)
            #pragma unroll
            for (int mf = 0; mf < 4; mf++)
                #pragma unroll
                for (int nf = 0; nf < 2; nf++)
                    acc[m][mf][nf] = f32x4{0.f, 0.f, 0.f, 0.f};

        uint4  a0[4], a1[4];
        float4 g0[2][2], u0[2][2], g1[2][2], u1[2][2];

#define LOADA(dst, kt) do { _Pragma("unroll") \
        for (int mf = 0; mf < 4; mf++) dst[mf] = *(const uint4*)(aP[mf] + (kt)); } while (0)
#define LOADB(dg, du, kt) do { _Pragma("unroll") \
        for (int nf = 0; nf < 2; nf++) { \
            const float4* pg = (const float4*)(gP[nf] + (kt)); \
            dg[nf][0] = pg[0]; dg[nf][1] = pg[1]; \
            const float4* pu = (const float4*)(uP[nf] + (kt)); \
            du[nf][0] = pu[0]; du[nf][1] = pu[1]; } } while (0)
#define COMPUTE(av, gv, uv) do { _Pragma("unroll") \
        for (int nf = 0; nf < 2; nf++) { \
            bf16x8 bg = cvt8(gv[nf][0], gv[nf][1]); \
            bf16x8 bu = cvt8(uv[nf][0], uv[nf][1]); \
            _Pragma("unroll") \
            for (int mf = 0; mf < 4; mf++) { \
                bf16x8 af = asbf(av[mf]); \
                acc[0][mf][nf] = __builtin_amdgcn_mfma_f32_16x16x32_bf16(af, bg, acc[0][mf][nf], 0, 0, 0); \
                acc[1][mf][nf] = __builtin_amdgcn_mfma_f32_16x16x32_bf16(af, bu, acc[1][mf][nf], 0, 0, 0); \
            } } } while (0)

        LOADA(a0, 0); LOADB(g0, u0, 0);
        for (int kt = 0; kt < K; kt += 64) {
            LOADA(a1, kt + 32); LOADB(g1, u1, kt + 32);
            COMPUTE(a0, g0, u0);
            if (kt + 64 < K) { LOADA(a0, kt + 64); LOADB(g0, u0, kt + 64); }
            COMPUTE(a1, g1, u1);
        }
#undef LOADA
#undef LOADB
#undef COMPUTE

        // epilogue: silu(gate)*up*wt -> bf16 H. D: col=lane&15, row=(lane>>4)*4+reg
        #pragma unroll
        for (int mf = 0; mf < 4; mf++)
            #pragma unroll
            for (int j = 0; j < 4; j++) {
                int m = wm0 + mf * 16 + lk * 4 + j;
                bool valid = GROUPED ? (mt * 128 + m < mcnt) : true;
                if (valid) {
                    size_t row; float wt;
                    if constexpr (GROUPED) {
                        size_t sl = (size_t)(mbase + mt * 128 + m);
                        row = sl; wt = slot_wt[sl];
                    } else { row = (size_t)(blockIdx.y * 128 + m); wt = 1.f; }
                    #pragma unroll
                    for (int nf = 0; nf < 2; nf++) {
                        int col = blockIdx.x * 64 + wn0 + nf * 16 + lm;
                        float g = acc[0][mf][nf][j], u = acc[1][mf][nf][j];
                        float hv = g / (1.f + __expf(-g)) * u * wt;
                        H[row * (size_t)N + col] = f2bf(hv);
                    }
                }
            }
    }
}

// ------- down proj, reg-streaming: out = Hb @ W^T (overwrite*sgate or atomic) -------
template<bool GROUPED>
__global__ __launch_bounds__(256, 3) void down_k(
    const u16* __restrict__ Hb, const float* __restrict__ W0, size_t bStride,
    float* __restrict__ outF,
    const int* __restrict__ slot_tok, const float* __restrict__ sgate,
    const int* __restrict__ cnt, const int* __restrict__ basearr,
    int K, int N)
{
    const int tid = threadIdx.x, w = tid >> 6, lane = tid & 63;
    const int lm = lane & 15, lk = lane >> 4;
    const int wm0 = (w >> 1) * 64, wn0 = (w & 1) * 32;
    const int e = GROUPED ? blockIdx.z : 0;
    const int mcnt = GROUPED ? cnt[e] : 128;
    const int mbase = GROUPED ? basearr[e] : 0;

    const float* bP[2];
    #pragma unroll
    for (int nf = 0; nf < 2; nf++) {
        size_t row = (size_t)(blockIdx.x * 64 + wn0 + nf * 16 + lm);
        bP[nf] = W0 + (size_t)e * bStride + row * K + lk * 8;
    }

    for (int mt = 0; GROUPED ? (mt * 128 < mcnt) : (mt == 0); ++mt) {
        const u16* aP[4];
        #pragma unroll
        for (int mf = 0; mf < 4; mf++) {
            int mrow = wm0 + mf * 16 + lm;
            int row;
            if constexpr (GROUPED) {
                int sl = mbase + mt * 128 + mrow;
                row = (mt * 128 + mrow < mcnt) ? sl : mbase;
            } else row = blockIdx.y * 128 + mrow;
            aP[mf] = Hb + (size_t)row * K + lk * 8;
        }

        f32x4 acc[4][2];
        #pragma unroll
        for (int mf = 0; mf < 4; mf++)
            #pragma unroll
            for (int nf = 0; nf < 2; nf++)
                acc[mf][nf] = f32x4{0.f, 0.f, 0.f, 0.f};

        uint4  a0[4], a1[4];
        float4 b0[2][2], b1[2][2];

#define LOADA(dst, kt) do { _Pragma("unroll") \
        for (int mf = 0; mf < 4; mf++) dst[mf] = *(const uint4*)(aP[mf] + (kt)); } while (0)
#define LOADB(db, kt) do { _Pragma("unroll") \
        for (int nf = 0; nf < 2; nf++) { \
            const float4* pb = (const float4*)(bP[nf] + (kt)); \
            db[nf][0] = pb[0]; db[nf][1] = pb[1]; } } while (0)
#define COMPUTE(av, bv) do { _Pragma("unroll") \
        for (int nf = 0; nf < 2; nf++) { \
            bf16x8 bf_ = cvt8(bv[nf][0], bv[nf][1]); \
            _Pragma("unroll") \
            for (int mf = 0; mf < 4; mf++) \
                acc[mf][nf] = __builtin_amdgcn_mfma_f32_16x16x32_bf16(asbf(av[mf]), bf_, acc[mf][nf], 0, 0, 0); \
        } } while (0)

        LOADA(a0, 0); LOADB(b0, 0);
        for (int kt = 0; kt < K; kt += 64) {
            LOADA(a1, kt + 32); LOADB(b1, kt + 32);
            COMPUTE(a0, b0);
            if (kt + 64 < K) { LOADA(a0, kt + 64); LOADB(b0, kt + 64); }
            COMPUTE(a1, b1);
        }
#undef LOADA
#undef LOADB
#undef COMPUTE

        #pragma unroll
        for (int mf = 0; mf < 4; mf++)
            #pragma unroll
            for (int j = 0; j < 4; j++) {
                int m = wm0 + mf * 16 + lk * 4 + j;
                bool valid = GROUPED ? (mt * 128 + m < mcnt) : true;
                if (valid) {
                    #pragma unroll
                    for (int nf = 0; nf < 2; nf++) {
                        int col = blockIdx.x * 64 + wn0 + nf * 16 + lm;
                        if constexpr (GROUPED) {
                            int tok = slot_tok[mbase + mt * 128 + m];
                            atomicAdd(&outF[(size_t)tok * N + col], acc[mf][nf][j]);
                        } else {
                            int tok = blockIdx.y * 128 + m;
                            outF[(size_t)tok * N + col] = sgate[tok] * acc[mf][nf][j];
                        }
                    }
                }
            }
    }
}

extern "C" void kernel_launch(void* const* d_in, const int* in_sizes, int n_in,
                              void* d_out, int out_size, void* d_ws, size_t ws_size,
                              hipStream_t stream)
{
    const float* x      = (const float*)d_in[0];
    const float* rw     = (const float*)d_in[1];
    const float* w_gate = (const float*)d_in[2];
    const float* w_up   = (const float*)d_in[3];
    const float* w_down = (const float*)d_in[4];
    const float* sw_g   = (const float*)d_in[5];
    const float* sw_u   = (const float*)d_in[6];
    const float* sw_d   = (const float*)d_in[7];
    const float* sgw    = (const float*)d_in[8];
    float* out = (float*)d_out;

    char* ws = (char*)d_ws;
    int*   cnt      = (int*)(ws + 0);        // ints 0..63
    int*   fill     = (int*)(ws + 256);      // ints 64..127
    int*   basea    = (int*)(ws + 512);
    float* sgate    = (float*)(ws + 768);
    float* topk_p   = (float*)(ws + 5120);
    int*   topk_i   = (int*)(ws + 21504);
    int*   slot_tok = (int*)(ws + 37888);
    float* slot_wt  = (float*)(ws + 54272);
    u16*   xb = (u16*)(ws + 71680);            // [1024][2048] bf16
    u16*   h  = xb + (size_t)TT * HD;          // [4096][1408] bf16
    u16*   hs = h + (size_t)4096 * ID;         // [1024][5632] bf16

    zero_k<<<1, 128, 0, stream>>>(cnt);        // zeros cnt + fill (bytes 0..511)
    xcvt_k<<<512, 256, 0, stream>>>(x, xb);
    router_k<<<TT, 64, 0, stream>>>(x, rw, sgw, topk_p, topk_i, cnt, sgate);
    prefix_k<<<1, 64, 0, stream>>>(cnt, basea);
    scatter_k<<<4, 256, 0, stream>>>(topk_p, topk_i, basea, fill, slot_tok, slot_wt);

    // routed fused gate+up -> h (slot-indexed)
    gu_k<true><<<dim3(ID / 64, 1, NE), 256, 0, stream>>>(
        xb, w_gate, w_up, (size_t)ID * HD, h,
        slot_tok, slot_wt, cnt, basea, HD, ID);
    // shared fused gate+up -> hs (token-indexed)
    gu_k<false><<<dim3(SID / 64, TT / 128, 1), 256, 0, stream>>>(
        xb, sw_g, sw_u, 0, hs,
        nullptr, nullptr, nullptr, nullptr, HD, SID);
    // shared down OVERWRITES out: out = sgate * (hs @ sw_down^T)
    down_k<false><<<dim3(HD / 64, TT / 128, 1), 256, 0, stream>>>(
        hs, sw_d, 0, out,
        nullptr, sgate, nullptr, nullptr, SID, HD);
    // routed down accumulates: out[tok] += h @ w_down[e]^T
    down_k<true><<<dim3(HD / 64, 1, NE), 256, 0, stream>>>(
        h, w_down, (size_t)HD * ID, out,
        slot_tok, nullptr, cnt, basea, ID, HD);
}

// Round 5
// 802.460 us; speedup vs baseline: 1.6705x; 1.6705x over previous
//
#include <hip/hip_runtime.h>
#include <hip/hip_bf16.h>

// QwenMoe: T=1024 H=2048 I=1408 E=60 SI=5632 topk=4, fp32 in/out.
// R5: global_load_lds staging + counted vmcnt + raw s_barrier (T3/T4 recipe):
// next tile's DMA stays in flight across barriers. Full 3-bit XOR chunk
// swizzle (rule #21: linear LDS dest, inverse-swizzled global src, swizzled
// read). A-side bf16 in LDS; B-side fp32 -> cvt_pk_bf16 on read.

typedef float  f32x4  __attribute__((ext_vector_type(4)));
typedef short  bf16x8 __attribute__((ext_vector_type(8)));
typedef unsigned short u16;
typedef unsigned int   u32;

constexpr int TT = 1024, HD = 2048, ID = 1408, NE = 60, SID = 5632, KTOP = 4;

#define GLDS(g, l) __builtin_amdgcn_global_load_lds( \
    (const __attribute__((address_space(1))) void*)(g), \
    (__attribute__((address_space(3))) void*)(l), 16, 0, 0)
#define WAITVM(n) asm volatile("s_waitcnt vmcnt(" #n ")" ::: "memory")
#define BAR() do { asm volatile("" ::: "memory"); \
    __builtin_amdgcn_s_barrier(); \
    asm volatile("" ::: "memory"); } while (0)

__device__ __forceinline__ u16 f2bf(float f) {
    union { float f; u32 u; } v; v.f = f;
    u32 r = v.u + 0x7FFFu + ((v.u >> 16) & 1u);   // RNE
    return (u16)(r >> 16);
}
__device__ __forceinline__ u32 cvtpk(float a, float b) {
    u32 r; asm("v_cvt_pk_bf16_f32 %0, %1, %2" : "=v"(r) : "v"(a), "v"(b));
    return r;
}
__device__ __forceinline__ bf16x8 cvt8(float4 a, float4 b) {
    union { u32 u[4]; bf16x8 v; } rr;
    rr.u[0] = cvtpk(a.x, a.y); rr.u[1] = cvtpk(a.z, a.w);
    rr.u[2] = cvtpk(b.x, b.y); rr.u[3] = cvtpk(b.z, b.w);
    return rr.v;
}

// ---------------- tiny utility kernels ----------------
__global__ void zero_k(int* __restrict__ p) { p[threadIdx.x] = 0; }

__global__ __launch_bounds__(256) void xcvt_k(const float* __restrict__ x, u16* __restrict__ xb)
{
    size_t i = ((size_t)blockIdx.x * 256 + threadIdx.x) * 16;
    const float4* p = (const float4*)(x + i);
    float4 f0 = p[0], f1 = p[1], f2 = p[2], f3 = p[3];
    uint4 o0, o1;
    o0.x = cvtpk(f0.x, f0.y); o0.y = cvtpk(f0.z, f0.w);
    o0.z = cvtpk(f1.x, f1.y); o0.w = cvtpk(f1.z, f1.w);
    o1.x = cvtpk(f2.x, f2.y); o1.y = cvtpk(f2.z, f2.w);
    o1.z = cvtpk(f3.x, f3.y); o1.w = cvtpk(f3.z, f3.w);
    ((uint4*)(xb + i))[0] = o0;
    ((uint4*)(xb + i))[1] = o1;
}

// ---------------- router ----------------
__global__ __launch_bounds__(64) void router_k(
    const float* __restrict__ x, const float* __restrict__ rw,
    const float* __restrict__ sgw,
    float* __restrict__ topk_p, int* __restrict__ topk_i,
    int* __restrict__ cnt, float* __restrict__ sgate)
{
    const int t = blockIdx.x, l = threadIdx.x;
    const float4* xr = ((const float4*)(x + (size_t)t * HD)) + l * 8;
    float4 xa[8];
    #pragma unroll
    for (int i = 0; i < 8; i++) xa[i] = xr[i];

    float le = 0.f;
    for (int e = 0; e < NE; e++) {
        const float4* wr = ((const float4*)(rw + (size_t)e * HD)) + l * 8;
        float a = 0.f;
        #pragma unroll
        for (int i = 0; i < 8; i++) {
            float4 wv = wr[i];
            a += xa[i].x * wv.x + xa[i].y * wv.y + xa[i].z * wv.z + xa[i].w * wv.w;
        }
        #pragma unroll
        for (int s = 32; s; s >>= 1) a += __shfl_xor(a, s);
        if (l == e) le = a;
    }
    {
        const float4* wr = ((const float4*)sgw) + l * 8;
        float a = 0.f;
        #pragma unroll
        for (int i = 0; i < 8; i++) {
            float4 wv = wr[i];
            a += xa[i].x * wv.x + xa[i].y * wv.y + xa[i].z * wv.z + xa[i].w * wv.w;
        }
        #pragma unroll
        for (int s = 32; s; s >>= 1) a += __shfl_xor(a, s);
        if (l == 0) sgate[t] = 1.f / (1.f + __expf(-a));
    }
    float mv = (l < NE) ? le : -3.4e38f;
    #pragma unroll
    for (int s = 32; s; s >>= 1) mv = fmaxf(mv, __shfl_xor(mv, s));
    float p = (l < NE) ? __expf(le - mv) : 0.f;
    float ss = p;
    #pragma unroll
    for (int s = 32; s; s >>= 1) ss += __shfl_xor(ss, s);
    p /= ss;
    float pv = (l < NE) ? p : -1.f;
    int   pi = l;
    float kp = 0.f; int ki = 0;
    for (int k = 0; k < KTOP; k++) {
        float bv = pv; int bi = pi;
        #pragma unroll
        for (int s = 32; s; s >>= 1) {
            float ov = __shfl_xor(bv, s); int oi = __shfl_xor(bi, s);
            if (ov > bv || (ov == bv && oi < bi)) { bv = ov; bi = oi; }
        }
        if (l == k) { kp = bv; ki = bi; }
        if (pi == bi) pv = -1.f;
    }
    if (l < KTOP) {
        topk_p[t * KTOP + l] = kp;
        topk_i[t * KTOP + l] = ki;
        atomicAdd(&cnt[ki], 1);
    }
}

__global__ __launch_bounds__(64) void prefix_k(const int* __restrict__ cnt, int* __restrict__ base)
{
    int l = threadIdx.x;
    if (l < NE) {
        int s = 0;
        for (int j = 0; j < l; j++) s += cnt[j];
        base[l] = s;
    }
}

__global__ __launch_bounds__(256) void scatter_k(
    const float* __restrict__ topk_p, const int* __restrict__ topk_i,
    const int* __restrict__ base, int* __restrict__ fill,
    int* __restrict__ slot_tok, float* __restrict__ slot_wt)
{
    int t = blockIdx.x * blockDim.x + threadIdx.x;
    if (t >= TT) return;
    for (int k = 0; k < KTOP; k++) {
        int e = topk_i[t * KTOP + k];
        int pos = atomicAdd(&fill[e], 1);
        int s = base[e] + pos;
        slot_tok[s] = t;
        slot_wt[s]  = topk_p[t * KTOP + k];
    }
}

// ------- fused gate+up: H = silu(A@Wg^T)*(A@Wu^T)*wt. Tile M128 x N64, BK=32.
// A bf16 via GLDS; Bg/Bu fp32 via GLDS; counted vmcnt(6); raw barriers.
template<bool GROUPED>
__global__ __launch_bounds__(256, 3) void gu_k(
    const u16* __restrict__ Xb,
    const float* __restrict__ Wg, const float* __restrict__ Wu, size_t bStride,
    u16* __restrict__ H,
    const int* __restrict__ slot_tok, const float* __restrict__ slot_wt,
    const int* __restrict__ cnt, const int* __restrict__ basearr,
    int K, int N)
{
    __shared__ u16   Asl[2][128 * 32];
    __shared__ float Bgsl[2][64 * 32];
    __shared__ float Busl[2][64 * 32];

    const int tid = threadIdx.x, w = tid >> 6, lane = tid & 63;
    const int lm = lane & 15, lk = lane >> 4;
    const int wm0 = (w >> 1) * 64, wn0 = (w & 1) * 32;
    const int e = GROUPED ? blockIdx.z : 0;
    const int mcnt = GROUPED ? cnt[e] : 128;
    const int mbase = GROUPED ? basearr[e] : 0;

    // inverse-swizzle source chunk offsets (elements)
    const int aCh = ((lane & 3) ^ ((lane >> 2) & 3)) << 3;   // bf16, 4 chunks/row
    const int bCh = ((lane & 7) ^ ((lane >> 3) & 7)) << 2;   // f32,  8 chunks/row

    // B global sources: wave w stages rows w*16 + j*8 + (lane>>3)
    const float* bgSrc[2]; const float* buSrc[2];
    #pragma unroll
    for (int j = 0; j < 2; j++) {
        size_t rB = (size_t)(blockIdx.x * 64 + w * 16 + j * 8 + (lane >> 3));
        bgSrc[j] = Wg + (size_t)e * bStride + rB * K + bCh;
        buSrc[j] = Wu + (size_t)e * bStride + rB * K + bCh;
    }

    // read-side swizzled LDS offsets
    int aOff[4], bOff[2][2];
    #pragma unroll
    for (int mf = 0; mf < 4; mf++) {
        int r = wm0 + mf * 16 + lm;
        aOff[mf] = r * 32 + ((lk ^ (r & 3)) << 3);
    }
    #pragma unroll
    for (int nf = 0; nf < 2; nf++) {
        int rb = wn0 + nf * 16 + lm;
        bOff[nf][0] = rb * 32 + ((((lk << 1)    ) ^ (rb & 7)) << 2);
        bOff[nf][1] = rb * 32 + ((((lk << 1) | 1) ^ (rb & 7)) << 2);
    }

    const int nk = K >> 5;

    for (int mt = 0; GROUPED ? (mt * 128 < mcnt) : (mt == 0); ++mt) {
        // A global sources: wave w stages rows w*32 + j*16 + (lane>>2)
        const u16* aSrc[2];
        #pragma unroll
        for (int j = 0; j < 2; j++) {
            int mrow = w * 32 + j * 16 + (lane >> 2);
            int row;
            if constexpr (GROUPED) {
                int sl = mbase + mt * 128 + mrow;
                row = (mt * 128 + mrow < mcnt) ? slot_tok[sl] : slot_tok[mbase];
            } else row = blockIdx.y * 128 + mrow;
            aSrc[j] = Xb + (size_t)row * K + aCh;
        }

        f32x4 acc[2][4][2];
        #pragma unroll
        for (int m = 0; m < 2; m++)
            #pragma unroll
            for (int mf = 0; mf < 4; mf++)
                #pragma unroll
                for (int nf = 0; nf < 2; nf++)
                    acc[m][mf][nf] = f32x4{0.f, 0.f, 0.f, 0.f};

        auto stage = [&](int b, int kt) {
            #pragma unroll
            for (int j = 0; j < 2; j++)
                GLDS(aSrc[j] + kt, &Asl[b][(w * 32 + j * 16) * 32]);
            #pragma unroll
            for (int j = 0; j < 2; j++) {
                GLDS(bgSrc[j] + kt, &Bgsl[b][(w * 16 + j * 8) * 32]);
                GLDS(buSrc[j] + kt, &Busl[b][(w * 16 + j * 8) * 32]);
            }
        };

        stage(0, 0);
        for (int t = 0; t < nk; ++t) {
            const int cur = t & 1;
            if (t + 1 < nk) { stage(cur ^ 1, (t + 1) << 5); WAITVM(6); }
            else WAITVM(0);
            BAR();                                // tile t ready; t+1 in flight
            const u16*   At  = Asl[cur];
            const float* Bgt = Bgsl[cur];
            const float* But = Busl[cur];
            bf16x8 af[4];
            #pragma unroll
            for (int mf = 0; mf < 4; mf++) af[mf] = *(const bf16x8*)&At[aOff[mf]];
            #pragma unroll
            for (int nf = 0; nf < 2; nf++) {
                bf16x8 bg = cvt8(*(const float4*)&Bgt[bOff[nf][0]],
                                 *(const float4*)&Bgt[bOff[nf][1]]);
                bf16x8 bu = cvt8(*(const float4*)&But[bOff[nf][0]],
                                 *(const float4*)&But[bOff[nf][1]]);
                #pragma unroll
                for (int mf = 0; mf < 4; mf++) {
                    acc[0][mf][nf] = __builtin_amdgcn_mfma_f32_16x16x32_bf16(af[mf], bg, acc[0][mf][nf], 0, 0, 0);
                    acc[1][mf][nf] = __builtin_amdgcn_mfma_f32_16x16x32_bf16(af[mf], bu, acc[1][mf][nf], 0, 0, 0);
                }
            }
            BAR();                                // all waves done reading tile t
        }

        // epilogue: silu(gate)*up*wt -> bf16 H. D: col=lane&15, row=(lane>>4)*4+reg
        #pragma unroll
        for (int mf = 0; mf < 4; mf++)
            #pragma unroll
            for (int j = 0; j < 4; j++) {
                int m = wm0 + mf * 16 + lk * 4 + j;
                bool valid = GROUPED ? (mt * 128 + m < mcnt) : true;
                if (valid) {
                    size_t row; float wt;
                    if constexpr (GROUPED) {
                        size_t sl = (size_t)(mbase + mt * 128 + m);
                        row = sl; wt = slot_wt[sl];
                    } else { row = (size_t)(blockIdx.y * 128 + m); wt = 1.f; }
                    #pragma unroll
                    for (int nf = 0; nf < 2; nf++) {
                        int col = blockIdx.x * 64 + wn0 + nf * 16 + lm;
                        float g = acc[0][mf][nf][j], u = acc[1][mf][nf][j];
                        float hv = g / (1.f + __expf(-g)) * u * wt;
                        H[row * (size_t)N + col] = f2bf(hv);
                    }
                }
            }
    }
}

// ------- down proj: out = Hb @ W^T (overwrite*sgate or atomicAdd). M128 x N64.
template<bool GROUPED>
__global__ __launch_bounds__(256, 4) void down_k(
    const u16* __restrict__ Hb, const float* __restrict__ W0, size_t bStride,
    float* __restrict__ outF,
    const int* __restrict__ slot_tok, const float* __restrict__ sgate,
    const int* __restrict__ cnt, const int* __restrict__ basearr,
    int K, int N)
{
    __shared__ u16   Asl[2][128 * 32];
    __shared__ float Bsl[2][64 * 32];

    const int tid = threadIdx.x, w = tid >> 6, lane = tid & 63;
    const int lm = lane & 15, lk = lane >> 4;
    const int wm0 = (w >> 1) * 64, wn0 = (w & 1) * 32;
    const int e = GROUPED ? blockIdx.z : 0;
    const int mcnt = GROUPED ? cnt[e] : 128;
    const int mbase = GROUPED ? basearr[e] : 0;

    const int aCh = ((lane & 3) ^ ((lane >> 2) & 3)) << 3;
    const int bCh = ((lane & 7) ^ ((lane >> 3) & 7)) << 2;

    const float* bSrc[2];
    #pragma unroll
    for (int j = 0; j < 2; j++) {
        size_t rB = (size_t)(blockIdx.x * 64 + w * 16 + j * 8 + (lane >> 3));
        bSrc[j] = W0 + (size_t)e * bStride + rB * K + bCh;
    }

    int aOff[4], bOff[2][2];
    #pragma unroll
    for (int mf = 0; mf < 4; mf++) {
        int r = wm0 + mf * 16 + lm;
        aOff[mf] = r * 32 + ((lk ^ (r & 3)) << 3);
    }
    #pragma unroll
    for (int nf = 0; nf < 2; nf++) {
        int rb = wn0 + nf * 16 + lm;
        bOff[nf][0] = rb * 32 + ((((lk << 1)    ) ^ (rb & 7)) << 2);
        bOff[nf][1] = rb * 32 + ((((lk << 1) | 1) ^ (rb & 7)) << 2);
    }

    const int nk = K >> 5;

    for (int mt = 0; GROUPED ? (mt * 128 < mcnt) : (mt == 0); ++mt) {
        const u16* aSrc[2];
        #pragma unroll
        for (int j = 0; j < 2; j++) {
            int mrow = w * 32 + j * 16 + (lane >> 2);
            size_t row;
            if constexpr (GROUPED) row = (size_t)(mbase + mt * 128 + mrow);  // h padded
            else                   row = (size_t)(blockIdx.y * 128 + mrow);
            aSrc[j] = Hb + row * K + aCh;
        }

        f32x4 acc[4][2];
        #pragma unroll
        for (int mf = 0; mf < 4; mf++)
            #pragma unroll
            for (int nf = 0; nf < 2; nf++)
                acc[mf][nf] = f32x4{0.f, 0.f, 0.f, 0.f};

        auto stage = [&](int b, int kt) {
            #pragma unroll
            for (int j = 0; j < 2; j++)
                GLDS(aSrc[j] + kt, &Asl[b][(w * 32 + j * 16) * 32]);
            #pragma unroll
            for (int j = 0; j < 2; j++)
                GLDS(bSrc[j] + kt, &Bsl[b][(w * 16 + j * 8) * 32]);
        };

        stage(0, 0);
        for (int t = 0; t < nk; ++t) {
            const int cur = t & 1;
            if (t + 1 < nk) { stage(cur ^ 1, (t + 1) << 5); WAITVM(4); }
            else WAITVM(0);
            BAR();
            const u16*   At = Asl[cur];
            const float* Bt = Bsl[cur];
            bf16x8 af[4];
            #pragma unroll
            for (int mf = 0; mf < 4; mf++) af[mf] = *(const bf16x8*)&At[aOff[mf]];
            #pragma unroll
            for (int nf = 0; nf < 2; nf++) {
                bf16x8 bf_ = cvt8(*(const float4*)&Bt[bOff[nf][0]],
                                  *(const float4*)&Bt[bOff[nf][1]]);
                #pragma unroll
                for (int mf = 0; mf < 4; mf++)
                    acc[mf][nf] = __builtin_amdgcn_mfma_f32_16x16x32_bf16(af[mf], bf_, acc[mf][nf], 0, 0, 0);
            }
            BAR();
        }

        #pragma unroll
        for (int mf = 0; mf < 4; mf++)
            #pragma unroll
            for (int j = 0; j < 4; j++) {
                int m = wm0 + mf * 16 + lk * 4 + j;
                bool valid = GROUPED ? (mt * 128 + m < mcnt) : true;
                if (valid) {
                    #pragma unroll
                    for (int nf = 0; nf < 2; nf++) {
                        int col = blockIdx.x * 64 + wn0 + nf * 16 + lm;
                        if constexpr (GROUPED) {
                            int tok = slot_tok[mbase + mt * 128 + m];
                            atomicAdd(&outF[(size_t)tok * N + col], acc[mf][nf][j]);
                        } else {
                            int tok = blockIdx.y * 128 + m;
                            outF[(size_t)tok * N + col] = sgate[tok] * acc[mf][nf][j];
                        }
                    }
                }
            }
    }
}

extern "C" void kernel_launch(void* const* d_in, const int* in_sizes, int n_in,
                              void* d_out, int out_size, void* d_ws, size_t ws_size,
                              hipStream_t stream)
{
    const float* x      = (const float*)d_in[0];
    const float* rw     = (const float*)d_in[1];
    const float* w_gate = (const float*)d_in[2];
    const float* w_up   = (const float*)d_in[3];
    const float* w_down = (const float*)d_in[4];
    const float* sw_g   = (const float*)d_in[5];
    const float* sw_u   = (const float*)d_in[6];
    const float* sw_d   = (const float*)d_in[7];
    const float* sgw    = (const float*)d_in[8];
    float* out = (float*)d_out;

    char* ws = (char*)d_ws;
    int*   cnt      = (int*)(ws + 0);
    int*   fill     = (int*)(ws + 256);
    int*   basea    = (int*)(ws + 512);
    float* sgate    = (float*)(ws + 768);
    float* topk_p   = (float*)(ws + 5120);
    int*   topk_i   = (int*)(ws + 21504);
    int*   slot_tok = (int*)(ws + 37888);
    float* slot_wt  = (float*)(ws + 54272);
    u16*   xb = (u16*)(ws + 71680);              // [1024][2048] bf16
    u16*   h  = xb + (size_t)TT * HD;            // [4096+128][1408] bf16 (padded)
    u16*   hs = h + (size_t)(4096 + 128) * ID;   // [1024][5632] bf16

    zero_k<<<1, 128, 0, stream>>>(cnt);          // zeros cnt + fill
    xcvt_k<<<512, 256, 0, stream>>>(x, xb);
    router_k<<<TT, 64, 0, stream>>>(x, rw, sgw, topk_p, topk_i, cnt, sgate);
    prefix_k<<<1, 64, 0, stream>>>(cnt, basea);
    scatter_k<<<4, 256, 0, stream>>>(topk_p, topk_i, basea, fill, slot_tok, slot_wt);

    // routed fused gate+up -> h (slot-indexed)
    gu_k<true><<<dim3(ID / 64, 1, NE), 256, 0, stream>>>(
        xb, w_gate, w_up, (size_t)ID * HD, h,
        slot_tok, slot_wt, cnt, basea, HD, ID);
    // shared fused gate+up -> hs (token-indexed)
    gu_k<false><<<dim3(SID / 64, TT / 128, 1), 256, 0, stream>>>(
        xb, sw_g, sw_u, 0, hs,
        nullptr, nullptr, nullptr, nullptr, HD, SID);
    // shared down OVERWRITES out: out = sgate * (hs @ sw_down^T)
    down_k<false><<<dim3(HD / 64, TT / 128, 1), 256, 0, stream>>>(
        hs, sw_d, 0, out,
        nullptr, sgate, nullptr, nullptr, SID, HD);
    // routed down accumulates: out[tok] += h @ w_down[e]^T
    down_k<true><<<dim3(HD / 64, 1, NE), 256, 0, stream>>>(
        h, w_down, (size_t)HD * ID, out,
        slot_tok, nullptr, cnt, basea, ID, HD);
}

// Round 6
// 727.802 us; speedup vs baseline: 1.8419x; 1.1026x over previous
//
#include <hip/hip_runtime.h>
#include <hip/hip_bf16.h>

// QwenMoe: T=1024 H=2048 I=1408 E=60 SI=5632 topk=4, fp32 in/out.
// R6: fuse 4 GEMMs -> 2 launches (flat-grid mode decode); 3-bit A-swizzle
// (2-way LDS reads); depth-2 prefetch in DOWN (3 buffers, vmcnt(8));
// all-atomic DOWN onto self-zeroed out (fast zero kernel, not rocclr fill).

typedef float  f32x4  __attribute__((ext_vector_type(4)));
typedef short  bf16x8 __attribute__((ext_vector_type(8)));
typedef unsigned short u16;
typedef unsigned int   u32;

constexpr int TT = 1024, HD = 2048, ID = 1408, NE = 60, SID = 5632, KTOP = 4;
constexpr int NBR_GU = (ID / 64) * NE;            // 1320 routed gu blocks
constexpr int NB_GU  = NBR_GU + (SID / 64) * (TT / 128);   // +704 shared = 2024
constexpr int NBS_DN = (HD / 64) * (TT / 128);    // 256 shared down blocks
constexpr int NB_DN  = NBS_DN + (HD / 64) * NE;   // +1920 routed = 2176

#define GLDS(g, l) __builtin_amdgcn_global_load_lds( \
    (const __attribute__((address_space(1))) void*)(g), \
    (__attribute__((address_space(3))) void*)(l), 16, 0, 0)
#define WAITVM(n) asm volatile("s_waitcnt vmcnt(" #n ")" ::: "memory")
#define BAR() do { asm volatile("" ::: "memory"); \
    __builtin_amdgcn_s_barrier(); \
    asm volatile("" ::: "memory"); } while (0)

__device__ __forceinline__ u16 f2bf(float f) {
    union { float f; u32 u; } v; v.f = f;
    u32 r = v.u + 0x7FFFu + ((v.u >> 16) & 1u);   // RNE
    return (u16)(r >> 16);
}
__device__ __forceinline__ u32 cvtpk(float a, float b) {
    u32 r; asm("v_cvt_pk_bf16_f32 %0, %1, %2" : "=v"(r) : "v"(a), "v"(b));
    return r;
}
__device__ __forceinline__ bf16x8 cvt8(float4 a, float4 b) {
    union { u32 u[4]; bf16x8 v; } rr;
    rr.u[0] = cvtpk(a.x, a.y); rr.u[1] = cvtpk(a.z, a.w);
    rr.u[2] = cvtpk(b.x, b.y); rr.u[3] = cvtpk(b.z, b.w);
    return rr.v;
}

// ---------------- tiny utility kernels ----------------
__global__ void zero_k(int* __restrict__ p) { p[threadIdx.x] = 0; }

__global__ __launch_bounds__(256) void zeroout_k(float* __restrict__ p) {
    ((float4*)p)[blockIdx.x * 256 + threadIdx.x] = make_float4(0.f, 0.f, 0.f, 0.f);
}

__global__ __launch_bounds__(256) void xcvt_k(const float* __restrict__ x, u16* __restrict__ xb)
{
    size_t i = ((size_t)blockIdx.x * 256 + threadIdx.x) * 16;
    const float4* p = (const float4*)(x + i);
    float4 f0 = p[0], f1 = p[1], f2 = p[2], f3 = p[3];
    uint4 o0, o1;
    o0.x = cvtpk(f0.x, f0.y); o0.y = cvtpk(f0.z, f0.w);
    o0.z = cvtpk(f1.x, f1.y); o0.w = cvtpk(f1.z, f1.w);
    o1.x = cvtpk(f2.x, f2.y); o1.y = cvtpk(f2.z, f2.w);
    o1.z = cvtpk(f3.x, f3.y); o1.w = cvtpk(f3.z, f3.w);
    ((uint4*)(xb + i))[0] = o0;
    ((uint4*)(xb + i))[1] = o1;
}

// ---------------- router ----------------
__global__ __launch_bounds__(64) void router_k(
    const float* __restrict__ x, const float* __restrict__ rw,
    const float* __restrict__ sgw,
    float* __restrict__ topk_p, int* __restrict__ topk_i,
    int* __restrict__ cnt, float* __restrict__ sgate)
{
    const int t = blockIdx.x, l = threadIdx.x;
    const float4* xr = ((const float4*)(x + (size_t)t * HD)) + l * 8;
    float4 xa[8];
    #pragma unroll
    for (int i = 0; i < 8; i++) xa[i] = xr[i];

    float le = 0.f;
    for (int e = 0; e < NE; e++) {
        const float4* wr = ((const float4*)(rw + (size_t)e * HD)) + l * 8;
        float a = 0.f;
        #pragma unroll
        for (int i = 0; i < 8; i++) {
            float4 wv = wr[i];
            a += xa[i].x * wv.x + xa[i].y * wv.y + xa[i].z * wv.z + xa[i].w * wv.w;
        }
        #pragma unroll
        for (int s = 32; s; s >>= 1) a += __shfl_xor(a, s);
        if (l == e) le = a;
    }
    {
        const float4* wr = ((const float4*)sgw) + l * 8;
        float a = 0.f;
        #pragma unroll
        for (int i = 0; i < 8; i++) {
            float4 wv = wr[i];
            a += xa[i].x * wv.x + xa[i].y * wv.y + xa[i].z * wv.z + xa[i].w * wv.w;
        }
        #pragma unroll
        for (int s = 32; s; s >>= 1) a += __shfl_xor(a, s);
        if (l == 0) sgate[t] = 1.f / (1.f + __expf(-a));
    }
    float mv = (l < NE) ? le : -3.4e38f;
    #pragma unroll
    for (int s = 32; s; s >>= 1) mv = fmaxf(mv, __shfl_xor(mv, s));
    float p = (l < NE) ? __expf(le - mv) : 0.f;
    float ss = p;
    #pragma unroll
    for (int s = 32; s; s >>= 1) ss += __shfl_xor(ss, s);
    p /= ss;
    float pv = (l < NE) ? p : -1.f;
    int   pi = l;
    float kp = 0.f; int ki = 0;
    for (int k = 0; k < KTOP; k++) {
        float bv = pv; int bi = pi;
        #pragma unroll
        for (int s = 32; s; s >>= 1) {
            float ov = __shfl_xor(bv, s); int oi = __shfl_xor(bi, s);
            if (ov > bv || (ov == bv && oi < bi)) { bv = ov; bi = oi; }
        }
        if (l == k) { kp = bv; ki = bi; }
        if (pi == bi) pv = -1.f;
    }
    if (l < KTOP) {
        topk_p[t * KTOP + l] = kp;
        topk_i[t * KTOP + l] = ki;
        atomicAdd(&cnt[ki], 1);
    }
}

__global__ __launch_bounds__(64) void prefix_k(const int* __restrict__ cnt, int* __restrict__ base)
{
    int l = threadIdx.x;
    if (l < NE) {
        int s = 0;
        for (int j = 0; j < l; j++) s += cnt[j];
        base[l] = s;
    }
}

__global__ __launch_bounds__(256) void scatter_k(
    const float* __restrict__ topk_p, const int* __restrict__ topk_i,
    const int* __restrict__ base, int* __restrict__ fill,
    int* __restrict__ slot_tok, float* __restrict__ slot_wt)
{
    int t = blockIdx.x * blockDim.x + threadIdx.x;
    if (t >= TT) return;
    for (int k = 0; k < KTOP; k++) {
        int e = topk_i[t * KTOP + k];
        int pos = atomicAdd(&fill[e], 1);
        int s = base[e] + pos;
        slot_tok[s] = t;
        slot_wt[s]  = topk_p[t * KTOP + k];
    }
}

// ======== fused GU: routed (bid<1320) + shared (else). Tile M128 x N64, BK=32.
__global__ __launch_bounds__(256, 3) void gu_all(
    const u16* __restrict__ Xb,
    const float* __restrict__ w_gate, const float* __restrict__ w_up,
    const float* __restrict__ sw_g, const float* __restrict__ sw_u,
    u16* __restrict__ h, u16* __restrict__ hs,
    const int* __restrict__ slot_tok, const float* __restrict__ slot_wt,
    const int* __restrict__ cnt, const int* __restrict__ basea)
{
    __shared__ u16   Asl[2][128 * 32];
    __shared__ float Bgsl[2][64 * 32];
    __shared__ float Busl[2][64 * 32];

    const int bid = blockIdx.x;
    const bool grouped = bid < NBR_GU;
    const int tid = threadIdx.x, w = tid >> 6, lane = tid & 63;
    const int lm = lane & 15, lk = lane >> 4;
    const int wm0 = (w >> 1) * 64, wn0 = (w & 1) * 32;

    int e = 0, my = 0, nb;
    const float *Wg, *Wu; u16* Hout; int Nout;
    if (grouped) {
        e = bid / 22; nb = bid % 22;
        Wg = w_gate + (size_t)e * ID * HD; Wu = w_up + (size_t)e * ID * HD;
        Hout = h; Nout = ID;
    } else {
        int sid = bid - NBR_GU; my = sid / 88; nb = sid % 88;
        Wg = sw_g; Wu = sw_u; Hout = hs; Nout = SID;
    }
    const int mcnt  = grouped ? cnt[e] : 128;
    const int mbase = grouped ? basea[e] : 0;

    // lane-constant inverse-swizzled source chunk offsets
    const int aCh = (((lane & 3) ^ ((lane >> 2) & 3) ^ ((lane >> 4) & 3))) << 3; // bf16
    const int bCh = ((lane & 7) ^ ((lane >> 3) & 7)) << 2;                        // f32

    const float* bgSrc[2]; const float* buSrc[2];
    #pragma unroll
    for (int j = 0; j < 2; j++) {
        size_t rB = (size_t)(nb * 64 + w * 16 + j * 8 + (lane >> 3));
        bgSrc[j] = Wg + rB * HD + bCh;
        buSrc[j] = Wu + rB * HD + bCh;
    }

    int aOff[4], bOff[2][2];
    #pragma unroll
    for (int mf = 0; mf < 4; mf++) {
        int r = wm0 + mf * 16 + lm;
        aOff[mf] = r * 32 + ((lk ^ (r & 3) ^ ((r >> 2) & 3)) << 3);
    }
    #pragma unroll
    for (int nf = 0; nf < 2; nf++) {
        int rb = wn0 + nf * 16 + lm;
        bOff[nf][0] = rb * 32 + ((((lk << 1)    ) ^ (rb & 7)) << 2);
        bOff[nf][1] = rb * 32 + ((((lk << 1) | 1) ^ (rb & 7)) << 2);
    }

    const int nk = HD >> 5;   // 64

    for (int mt = 0; grouped ? (mt * 128 < mcnt) : (mt == 0); ++mt) {
        const u16* aSrc[2];
        #pragma unroll
        for (int j = 0; j < 2; j++) {
            int mrow = w * 32 + j * 16 + (lane >> 2);
            int row;
            if (grouped) {
                int sl = mbase + mt * 128 + mrow;
                row = (mt * 128 + mrow < mcnt) ? slot_tok[sl] : slot_tok[mbase];
            } else row = my * 128 + mrow;
            aSrc[j] = Xb + (size_t)row * HD + aCh;
        }

        f32x4 accG[4][2], accU[4][2];
        #pragma unroll
        for (int mf = 0; mf < 4; mf++)
            #pragma unroll
            for (int nf = 0; nf < 2; nf++) {
                accG[mf][nf] = f32x4{0.f, 0.f, 0.f, 0.f};
                accU[mf][nf] = f32x4{0.f, 0.f, 0.f, 0.f};
            }

        auto stage = [&](int b, int kt) {
            #pragma unroll
            for (int j = 0; j < 2; j++)
                GLDS(aSrc[j] + kt, &Asl[b][(w * 32 + j * 16) * 32]);
            #pragma unroll
            for (int j = 0; j < 2; j++) {
                GLDS(bgSrc[j] + kt, &Bgsl[b][(w * 16 + j * 8) * 32]);
                GLDS(buSrc[j] + kt, &Busl[b][(w * 16 + j * 8) * 32]);
            }
        };

        stage(0, 0);
        for (int t = 0; t < nk; ++t) {
            const int cur = t & 1;
            if (t + 1 < nk) { stage(cur ^ 1, (t + 1) << 5); WAITVM(6); }
            else WAITVM(0);
            BAR();
            const u16*   At  = Asl[cur];
            const float* Bgt = Bgsl[cur];
            const float* But = Busl[cur];
            bf16x8 af[4];
            #pragma unroll
            for (int mf = 0; mf < 4; mf++) af[mf] = *(const bf16x8*)&At[aOff[mf]];
            #pragma unroll
            for (int nf = 0; nf < 2; nf++) {
                bf16x8 bg = cvt8(*(const float4*)&Bgt[bOff[nf][0]],
                                 *(const float4*)&Bgt[bOff[nf][1]]);
                bf16x8 bu = cvt8(*(const float4*)&But[bOff[nf][0]],
                                 *(const float4*)&But[bOff[nf][1]]);
                #pragma unroll
                for (int mf = 0; mf < 4; mf++) {
                    accG[mf][nf] = __builtin_amdgcn_mfma_f32_16x16x32_bf16(af[mf], bg, accG[mf][nf], 0, 0, 0);
                    accU[mf][nf] = __builtin_amdgcn_mfma_f32_16x16x32_bf16(af[mf], bu, accU[mf][nf], 0, 0, 0);
                }
            }
            BAR();
        }

        // epilogue: silu(g)*u*wt -> bf16. D: col=lane&15, row=(lane>>4)*4+reg
        #pragma unroll
        for (int mf = 0; mf < 4; mf++)
            #pragma unroll
            for (int j = 0; j < 4; j++) {
                int m = wm0 + mf * 16 + lk * 4 + j;
                bool valid = grouped ? (mt * 128 + m < mcnt) : true;
                if (valid) {
                    size_t row; float wt;
                    if (grouped) {
                        size_t sl = (size_t)(mbase + mt * 128 + m);
                        row = sl; wt = slot_wt[sl];
                    } else { row = (size_t)(my * 128 + m); wt = 1.f; }
                    #pragma unroll
                    for (int nf = 0; nf < 2; nf++) {
                        int col = nb * 64 + wn0 + nf * 16 + lm;
                        float g = accG[mf][nf][j], u = accU[mf][nf][j];
                        float hv = g / (1.f + __expf(-g)) * u * wt;
                        Hout[row * (size_t)Nout + col] = f2bf(hv);
                    }
                }
            }
    }
}

// ======== fused DOWN: shared (bid<256, K=5632) + routed (else, K=1408).
// All-atomicAdd onto pre-zeroed out. Depth-2 pipeline, 3 LDS buffers.
__global__ __launch_bounds__(256, 3) void down_all(
    const u16* __restrict__ h, const u16* __restrict__ hs,
    const float* __restrict__ w_down, const float* __restrict__ sw_d,
    float* __restrict__ outF,
    const int* __restrict__ slot_tok, const float* __restrict__ sgate,
    const int* __restrict__ cnt, const int* __restrict__ basea)
{
    __shared__ u16   Asl[3][128 * 32];
    __shared__ float Bsl[3][64 * 32];

    const int bid = blockIdx.x;
    const bool shared_m = bid < NBS_DN;
    const int tid = threadIdx.x, w = tid >> 6, lane = tid & 63;
    const int lm = lane & 15, lk = lane >> 4;
    const int wm0 = (w >> 1) * 64, wn0 = (w & 1) * 32;

    int e = 0, my = 0, nb, K;
    const u16* Ap; const float* Wp;
    if (shared_m) {
        my = bid / 32; nb = bid % 32; K = SID; Ap = hs; Wp = sw_d;
    } else {
        int rid = bid - NBS_DN; e = rid / 32; nb = rid % 32; K = ID;
        Ap = h; Wp = w_down + (size_t)e * HD * ID;
    }
    const int mcnt  = shared_m ? 128 : cnt[e];
    const int mbase = shared_m ? 0 : basea[e];

    const int aCh = (((lane & 3) ^ ((lane >> 2) & 3) ^ ((lane >> 4) & 3))) << 3;
    const int bCh = ((lane & 7) ^ ((lane >> 3) & 7)) << 2;

    const float* bSrc[2];
    #pragma unroll
    for (int j = 0; j < 2; j++) {
        size_t rB = (size_t)(nb * 64 + w * 16 + j * 8 + (lane >> 3));
        bSrc[j] = Wp + rB * K + bCh;
    }

    int aOff[4], bOff[2][2];
    #pragma unroll
    for (int mf = 0; mf < 4; mf++) {
        int r = wm0 + mf * 16 + lm;
        aOff[mf] = r * 32 + ((lk ^ (r & 3) ^ ((r >> 2) & 3)) << 3);
    }
    #pragma unroll
    for (int nf = 0; nf < 2; nf++) {
        int rb = wn0 + nf * 16 + lm;
        bOff[nf][0] = rb * 32 + ((((lk << 1)    ) ^ (rb & 7)) << 2);
        bOff[nf][1] = rb * 32 + ((((lk << 1) | 1) ^ (rb & 7)) << 2);
    }

    const int nk = K >> 5;   // 176 shared, 44 routed

    for (int mt = 0; shared_m ? (mt == 0) : (mt * 128 < mcnt); ++mt) {
        const u16* aSrc[2];
        #pragma unroll
        for (int j = 0; j < 2; j++) {
            int mrow = w * 32 + j * 16 + (lane >> 2);
            size_t row = shared_m ? (size_t)(my * 128 + mrow)
                                  : (size_t)(mbase + mt * 128 + mrow);  // h padded
            aSrc[j] = Ap + row * K + aCh;
        }

        f32x4 acc[4][2];
        #pragma unroll
        for (int mf = 0; mf < 4; mf++)
            #pragma unroll
            for (int nf = 0; nf < 2; nf++) acc[mf][nf] = f32x4{0.f, 0.f, 0.f, 0.f};

        auto stage = [&](int b, int kt) {
            #pragma unroll
            for (int j = 0; j < 2; j++)
                GLDS(aSrc[j] + kt, &Asl[b][(w * 32 + j * 16) * 32]);
            #pragma unroll
            for (int j = 0; j < 2; j++)
                GLDS(bSrc[j] + kt, &Bsl[b][(w * 16 + j * 8) * 32]);
        };
        auto comp = [&](int b) {
            const u16*   At = Asl[b];
            const float* Bt = Bsl[b];
            bf16x8 af[4];
            #pragma unroll
            for (int mf = 0; mf < 4; mf++) af[mf] = *(const bf16x8*)&At[aOff[mf]];
            #pragma unroll
            for (int nf = 0; nf < 2; nf++) {
                bf16x8 bf_ = cvt8(*(const float4*)&Bt[bOff[nf][0]],
                                  *(const float4*)&Bt[bOff[nf][1]]);
                #pragma unroll
                for (int mf = 0; mf < 4; mf++)
                    acc[mf][nf] = __builtin_amdgcn_mfma_f32_16x16x32_bf16(af[mf], bf_, acc[mf][nf], 0, 0, 0);
            }
        };

        stage(0, 0); stage(1, 32);
        int t = 0, cb = 0;
        for (; t + 2 < nk; ++t) {
            int sbuf = cb - 1; if (sbuf < 0) sbuf += 3;    // (cb+2)%3
            stage(sbuf, (t + 2) << 5);
            WAITVM(8); BAR(); comp(cb); BAR();
            cb = (cb + 1 == 3) ? 0 : cb + 1;
        }
        WAITVM(4); BAR(); comp(cb); BAR();
        cb = (cb + 1 == 3) ? 0 : cb + 1;
        WAITVM(0); BAR(); comp(cb); BAR();

        #pragma unroll
        for (int mf = 0; mf < 4; mf++)
            #pragma unroll
            for (int j = 0; j < 4; j++) {
                int m = wm0 + mf * 16 + lk * 4 + j;
                if (mt * 128 + m < mcnt) {
                    int tok; float scale;
                    if (shared_m) { tok = my * 128 + m; scale = sgate[tok]; }
                    else          { tok = slot_tok[mbase + mt * 128 + m]; scale = 1.f; }
                    #pragma unroll
                    for (int nf = 0; nf < 2; nf++) {
                        int col = nb * 64 + wn0 + nf * 16 + lm;
                        atomicAdd(&outF[(size_t)tok * HD + col], scale * acc[mf][nf][j]);
                    }
                }
            }
    }
}

extern "C" void kernel_launch(void* const* d_in, const int* in_sizes, int n_in,
                              void* d_out, int out_size, void* d_ws, size_t ws_size,
                              hipStream_t stream)
{
    const float* x      = (const float*)d_in[0];
    const float* rw     = (const float*)d_in[1];
    const float* w_gate = (const float*)d_in[2];
    const float* w_up   = (const float*)d_in[3];
    const float* w_down = (const float*)d_in[4];
    const float* sw_g   = (const float*)d_in[5];
    const float* sw_u   = (const float*)d_in[6];
    const float* sw_d   = (const float*)d_in[7];
    const float* sgw    = (const float*)d_in[8];
    float* out = (float*)d_out;

    char* ws = (char*)d_ws;
    int*   cnt      = (int*)(ws + 0);
    int*   fill     = (int*)(ws + 256);
    int*   basea    = (int*)(ws + 512);
    float* sgate    = (float*)(ws + 768);
    float* topk_p   = (float*)(ws + 5120);
    int*   topk_i   = (int*)(ws + 21504);
    int*   slot_tok = (int*)(ws + 37888);
    float* slot_wt  = (float*)(ws + 54272);
    u16*   xb = (u16*)(ws + 71680);              // [1024][2048] bf16
    u16*   h  = xb + (size_t)TT * HD;            // [4096+128][1408] bf16 (padded)
    u16*   hs = h + (size_t)(4096 + 128) * ID;   // [1024][5632] bf16

    zero_k<<<1, 128, 0, stream>>>(cnt);                       // cnt + fill
    zeroout_k<<<TT * HD / 1024, 256, 0, stream>>>(out);       // 8.4 MB fast zero
    xcvt_k<<<512, 256, 0, stream>>>(x, xb);
    router_k<<<TT, 64, 0, stream>>>(x, rw, sgw, topk_p, topk_i, cnt, sgate);
    prefix_k<<<1, 64, 0, stream>>>(cnt, basea);
    scatter_k<<<4, 256, 0, stream>>>(topk_p, topk_i, basea, fill, slot_tok, slot_wt);

    gu_all<<<NB_GU, 256, 0, stream>>>(
        xb, w_gate, w_up, sw_g, sw_u, h, hs,
        slot_tok, slot_wt, cnt, basea);

    down_all<<<NB_DN, 256, 0, stream>>>(
        h, hs, w_down, sw_d, out,
        slot_tok, sgate, cnt, basea);
}